// Round 11
// baseline (41.838 us; speedup 1.0000x reference)
//
#include <hip/hip_runtime.h>

#define NBATCH 8
#define HH 256
#define WW 256
#define CC 64
#define HWPTS 65536   // HH*WW
#define NSTEPS_ 50

typedef float vf4 __attribute__((ext_vector_type(4)));

// ---------------------------------------------------------------------------
// Single fused kernel, fine-grained: 4096 blocks x 128 thr; block = half an
// image row (128 points) of one batch. batch = bid&7 -> XCD.
// Step 0: threads 0..31 build this batch's 24 affine matrices A into LDS
//   (f64 inverse, f32 einsum — op-identical to R2's kernel 1).
// Phase 1: each thread integrates its point (A float2-packed in LDS).
// Phase 2: 4 iterations x 4-point groups: 16 float4 gathers issued
//   back-to-back, then 4 blends + nontemporal stores.
// Rationale: 2-wave WGs pack ~16 WGs/CU -> higher occupancy, 16 block
// generations -> staggered phases, smaller exposed integrate bursts/tail.
// ---------------------------------------------------------------------------
__global__ __launch_bounds__(128, 8) void cpab_fused(const float* __restrict__ xin,
                                                     const float* __restrict__ theta,
                                                     float* __restrict__ out) {
  __shared__ float2 sA2[96];
  __shared__ int    sOff[128];
  __shared__ float4 sW[128];

  int tid = threadIdx.x;
  int bid = blockIdx.x;            // 4096 blocks
  int b = bid & 7;                 // batch == XCD
  int lt = bid >> 3;               // tile 0..511 within batch (half-row)
  int base_hw = lt << 7;           // 128 points per tile

  // ---- step 0: build A for batch b (threads 0..31, one per triangle) ----
  if (tid < 32) {
    int t = tid;
    int cell = t >> 2, k = t & 3;
    int ci = cell & 1, cj = cell >> 1;
    int ll = cj * 3 + ci;
    int lr = ll + 1, ul = ll + 3, ur = ll + 4;
    int cen = 15 + cj * 2 + ci;
    int v0, v1, v2 = cen;
    if (k == 0)      { v0 = ll; v1 = lr; }
    else if (k == 1) { v0 = lr; v1 = ur; }
    else if (k == 2) { v0 = ur; v1 = ul; }
    else             { v0 = ul; v1 = ll; }

    int vs[3] = {v0, v1, v2};
    double xs[3], ys[3];
    float Vx[3], Vy[3];
    for (int q = 0; q < 3; ++q) {
      int v = vs[q];
      if (v < 15) { xs[q] = (double)(v % 3) * 0.5; ys[q] = (double)(v / 3) * 0.25; }
      else { int u = v - 15; xs[q] = ((double)(u & 1) + 0.5) * 0.5;
             ys[q] = ((double)(u >> 1) + 0.5) * 0.25; }
      int s = (v == 4) ? 0 : (v == 7) ? 1 : (v == 10) ? 2 : (v >= 15) ? (v - 12) : -1;
      if (s >= 0) { Vx[q] = theta[b * 22 + 2 * s]; Vy[q] = theta[b * 22 + 2 * s + 1]; }
      else        { Vx[q] = 0.f; Vy[q] = 0.f; }
    }
    double x0 = xs[0], x1 = xs[1], x2 = xs[2];
    double y0 = ys[0], y1 = ys[1], y2 = ys[2];
    double det = x0 * (y1 - y2) - x1 * (y0 - y2) + x2 * (y0 - y1);
    // P = [[x0,x1,x2],[y0,y1,y2],[1,1,1]];  inv = adj^T / det
    double inv[3][3] = {
        {y1 - y2, x2 - x1, x1 * y2 - x2 * y1},
        {y2 - y0, x0 - x2, x2 * y0 - x0 * y2},
        {y0 - y1, x1 - x0, x0 * y1 - x1 * y0}};
    for (int w = 0; w < 3; ++w) {
      float i0 = (float)(inv[0][w] / det);
      float i1 = (float)(inv[1][w] / det);
      float i2 = (float)(inv[2][w] / det);
      float ax = __fadd_rn(__fadd_rn(__fmul_rn(Vx[0], i0), __fmul_rn(Vx[1], i1)),
                           __fmul_rn(Vx[2], i2));
      float ay = __fadd_rn(__fadd_rn(__fmul_rn(Vy[0], i0), __fmul_rn(Vy[1], i1)),
                           __fmul_rn(Vy[2], i2));
      ((float*)sA2)[(w * 32 + t) * 2]     = ax;
      ((float*)sA2)[(w * 32 + t) * 2 + 1] = ay;
    }
  }
  __syncthreads();

  // ---- phase 1: integrate own point ----
  {
    int hw = base_hw + tid;
    int w = hw & 255, h = hw >> 8;
    // np.linspace(0,1,256): i * (1/255) with exact endpoint
    float px = (w == 255) ? 1.0f : __fmul_rn((float)w, 1.0f / 255.0f);
    float py = (h == 255) ? 1.0f : __fmul_rn((float)h, 1.0f / 255.0f);
#pragma unroll 1
    for (int s = 0; s < NSTEPS_; ++s) {
      float xc = fminf(fmaxf(px, 0.f), 1.f) * 2.0f;   // exact (*2)
      float yc = fminf(fmaxf(py, 0.f), 1.f) * 4.0f;   // exact (*4)
      float cxf = fminf(floorf(xc), 1.0f);
      float cyf = fminf(floorf(yc), 3.0f);
      float xr = xc - cxf, yr = yc - cyf;
      int tri = (yr <= xr) ? ((yr <= 1.0f - xr) ? 0 : 1)
                           : ((yr <= 1.0f - xr) ? 3 : 2);
      int cid = ((((int)cyf) << 1) + (int)cxf) * 4 + tri;
      float2 q0 = sA2[cid];        // {a00, a10}
      float2 q1 = sA2[32 + cid];   // {a01, a11}
      float2 q2 = sA2[64 + cid];   // {a02, a12}
      float vx = __fadd_rn(__fadd_rn(__fmul_rn(q0.x, px), __fmul_rn(q1.x, py)), q2.x);
      float vy = __fadd_rn(__fadd_rn(__fmul_rn(q0.y, px), __fmul_rn(q1.y, py)), q2.y);
      px = __fadd_rn(px, __fmul_rn(0.02f, vx));
      py = __fadd_rn(py, __fmul_rn(0.02f, vy));
    }
    float gx = __fmul_rn(fminf(fmaxf(px, 0.f), 1.f), 255.0f);
    float gy = __fmul_rn(fminf(fmaxf(py, 0.f), 1.f), 255.0f);
    int ix = min((int)gx, 254);   // gx >= 0 so (int) == floor
    int iy = min((int)gy, 254);
    float wx = __fadd_rn(gx, -(float)ix);
    float wy = __fadd_rn(gy, -(float)iy);
    sOff[tid] = (iy << 8) + ix;
    float4 w4;
    w4.x = (1.f - wx) * (1.f - wy);
    w4.y = wx * (1.f - wy);
    w4.z = (1.f - wx) * wy;
    w4.w = wx * wy;
    sW[tid] = w4;
  }
  __syncthreads();

  // ---- phase 2: gather + blend + store ----
  const float4* xb4 = (const float4*)(xin + (size_t)b * ((size_t)HWPTS * CC));
  float* ob = out + ((size_t)b * HWPTS + base_hw) * CC;
  int lane_c = tid & 15;     // channel chunk 0..15
  int lane_p = tid >> 4;     // point sub-index 0..7

#pragma unroll
  for (int r = 0; r < 4; ++r) {
    float4 L[4][4];
    float4 W[4];
    const float4* q[4];
#pragma unroll
    for (int g = 0; g < 4; ++g) {
      int p = r * 8 + lane_p + g * 32;
      int off = sOff[p];
      W[g] = sW[p];
      q[g] = xb4 + ((size_t)off << 4) + lane_c;
    }
#pragma unroll
    for (int g = 0; g < 4; ++g) {
      L[g][0] = q[g][0];
      L[g][1] = q[g][16];              // x0+1
      L[g][2] = q[g][16 * 256];        // y0+1
      L[g][3] = q[g][16 * 256 + 16];   // x0+1, y0+1
    }
#pragma unroll
    for (int g = 0; g < 4; ++g) {
      int p = r * 8 + lane_p + g * 32;
      vf4 o;
      o.x = L[g][0].x * W[g].x + L[g][1].x * W[g].y + L[g][2].x * W[g].z + L[g][3].x * W[g].w;
      o.y = L[g][0].y * W[g].x + L[g][1].y * W[g].y + L[g][2].y * W[g].z + L[g][3].y * W[g].w;
      o.z = L[g][0].z * W[g].x + L[g][1].z * W[g].y + L[g][2].z * W[g].z + L[g][3].z * W[g].w;
      o.w = L[g][0].w * W[g].x + L[g][1].w * W[g].y + L[g][2].w * W[g].z + L[g][3].w * W[g].w;
      __builtin_nontemporal_store(o, (vf4*)(ob + (size_t)p * CC + (lane_c << 2)));
    }
  }
}

extern "C" void kernel_launch(void* const* d_in, const int* in_sizes, int n_in,
                              void* d_out, int out_size, void* d_ws, size_t ws_size,
                              hipStream_t stream) {
  const float* x     = (const float*)d_in[0];   // (8,256,256,64) f32
  const float* theta = (const float*)d_in[1];   // (8,22) f32
  float* out  = (float*)d_out;                  // (8,256,256,64) f32

  cpab_fused<<<NBATCH * HWPTS / 128, 128, 0, stream>>>(x, theta, out);
}